// Round 13
// baseline (22357.607 us; speedup 1.0000x reference)
//
#include <hip/hip_runtime.h>

#define T_STEPS 4096
#define DIN     512
#define R_DIM   4096
#define DOUT    512
#define NINT    (R_DIM + DIN)   // 4608
#define NBLK    256
#define NTHR    512
#define NUNIT   2048            // 8B LL units per buffer; unit u = rows {2u,2u+1} bf16
#define LEAKF   0.9f

typedef float f32x4 __attribute__((ext_vector_type(4)));
typedef unsigned int u32;
typedef u32 u32x2 __attribute__((ext_vector_type(2)));
typedef u32 u32x4 __attribute__((ext_vector_type(4)));
typedef unsigned short u16;

// tanh via hardware exp2: tanh(x) = 1 - 2/(1 + e^{2x})
__device__ __forceinline__ float fast_tanh(float x)
{
    float e = __builtin_amdgcn_exp2f(x * 2.885390081777927f);
    return 1.0f - 2.0f * __builtin_amdgcn_rcpf(1.0f + e);
}

__device__ __forceinline__ u32 f2bf(float f)   // RNE f32 -> bf16 bits
{
    u32 u = __float_as_uint(f);
    return (u + 0x7FFFu + ((u >> 16) & 1u)) >> 16;
}
__device__ __forceinline__ float bfLO(u32 u) { return __uint_as_float(u << 16); }
__device__ __forceinline__ float bfHI(u32 u) { return __uint_as_float(u & 0xFFFF0000u); }

// Butterfly reduce of TWO values across 64 lanes: even lanes end with full
// sum of a0, odd lanes full sum of a1.
__device__ __forceinline__ float wave_reduce2(float a0, float a1, int lane)
{
    a0 += __shfl_xor(a0, 1);
    a1 += __shfl_xor(a1, 1);
    float b = (lane & 1) ? a1 : a0;
    b += __shfl_xor(b, 2);
    b += __shfl_xor(b, 4);
    b += __shfl_xor(b, 8);
    b += __shfl_xor(b, 16);
    b += __shfl_xor(b, 32);
    return b;
}

// One-time Wres f32 -> bf16 conversion into d_ws (RNE).
__global__ void conv_bf16(const float* __restrict__ src, u32* __restrict__ dst,
                          int n4)
{
    int idx = blockIdx.x * blockDim.x + threadIdx.x;
    int stride = gridDim.x * blockDim.x;
    for (int i = idx; i < n4; i += stride) {
        f32x4 v = *(const f32x4*)(src + (size_t)i * 4);
        u32x2 o;
        o.x = f2bf(v[0]) | (f2bf(v[1]) << 16);
        o.y = f2bf(v[2]) | (f2bf(v[3]) << 16);
        *(u32x2*)(dst + (size_t)i * 2) = o;
    }
}

// ---------------------------------------------------------------------------
// Persistent fused ESN: exact r9 skeleton (best measured: 10.34 ms) with
// bf16-converted Wres. Rationale: VGPR=108 across all rounds proves Wres is
// re-streamed every step (256KB/CU); per-XCD working set 8MB vs 4MB L2 means
// ~32MB/step spills to the Infinity Cache -- the same fabric carrying the LL
// exchange, inflating every poll RTT. bf16 weights halve the working set to
// exactly L2 size, removing the LLC weight traffic after warm-up.
// Thread k-assignment for the matvec: k = lane*8 + c*512 + j (j<8, c<8), so
// one dwordx4 load = 8 bf16 weights; states read as 2 x ds_read_b128.
// Everything else (LL protocol, poll loop, single barrier, readout by waves
// 0/1, proj prefetch) is byte-for-byte r9 -- the poll loop is untouchable
// (r6/r10/r11 each regressed 2-3ms perturbing it).
// ---------------------------------------------------------------------------
__global__ __launch_bounds__(NTHR, 2) void esn_fused(
    const float* __restrict__ x,       // (T, DIN)
    const float* __restrict__ Win_w,   // (R, DIN)
    const float* __restrict__ Win_b,   // (R)
    const u16*   __restrict__ wres_bf, // (R, R) bf16 (in d_ws)
    const float* __restrict__ Wout_w,  // (DOUT, NINT)
    const float* __restrict__ Wout_b,  // (DOUT)
    float* __restrict__ y,             // (T, DOUT)
    u32x2* __restrict__ comm)          // 2 * NUNIT units (d_ws)
{
    const int tid  = threadIdx.x;
    const int wave = tid >> 6;
    const int lane = tid & 63;
    const int bid  = blockIdx.x;
    const int row_e = (bid << 4) + (wave << 1);

    __shared__ float s_lds[2][R_DIM];       // 32 KB, parity double-buffer
    __shared__ float wout_lds[2 * NINT];    // 36.9 KB

    // ---- one-time staging ----
    {
        const float* wsrc = Wout_w + (size_t)(bid << 1) * NINT;
        for (int idx = tid; idx < 2 * NINT; idx += NTHR)
            wout_lds[idx] = wsrc[idx];
    }
    float wb = 0.f;
    if (wave < 2 && lane == 0) wb = Wout_b[(bid << 1) + wave];

    // bf16 weight row bases (u32 units: row = 2048 u32; lane*8 bf16 = lane*4 u32)
    const u32* wrow0 = (const u32*)(wres_bf + (size_t)row_e * R_DIM) + (lane << 2);
    const u32* wrow1 = (const u32*)(wres_bf + (size_t)(row_e + 1) * R_DIM) + (lane << 2);

    f32x4 win[2][2];
    {
        const float* ip = Win_w + (size_t)row_e * DIN + (lane << 2);
#pragma unroll
        for (int r = 0; r < 2; ++r)
#pragma unroll
            for (int c = 0; c < 2; ++c)
                win[r][c] = *(const f32x4*)(ip + (size_t)r * DIN + (c << 8));
    }
    const float bias_e = Win_b[row_e];
    const float bias_o = Win_b[row_e + 1];
    float s_old_e = 0.f, s_old_o = 0.f;   // lane 0's copy is authoritative

    float a0, a1;

#define PROJ(xrow)                                                        \
    {                                                                     \
        f32x4 xv0 = *(const f32x4*)((xrow) + (lane << 2));                \
        f32x4 xv1 = *(const f32x4*)((xrow) + 256 + (lane << 2));          \
        a0 = 0.f; a1 = 0.f;                                               \
        _Pragma("unroll")                                                 \
        for (int q = 0; q < 4; ++q) {                                     \
            a0 += win[0][0][q] * xv0[q] + win[0][1][q] * xv1[q];          \
            a1 += win[1][0][q] * xv0[q] + win[1][1][q] * xv1[q];          \
        }                                                                 \
    }

    // ---- step 0: s0 = tanh(Win x0 + b); publish tag 1, buffer 0 ----
    {
        PROJ(x);
        float b = wave_reduce2(a0, a1, lane);
        float se = __shfl(b, 0) + bias_e;
        float so = __shfl(b, 1) + bias_o;
        float sn_e = fast_tanh(se);
        float sn_o = fast_tanh(so);
        s_old_e = sn_e; s_old_o = sn_o;
        if (lane == 0) {
            u32x2 pkt;
            pkt.x = f2bf(sn_e) | (f2bf(sn_o) << 16);
            pkt.y = 1u;
            u32x2* dst = comm + (bid << 3) + wave;
            asm volatile("global_store_dwordx2 %0, %1, off sc0 sc1"
                         :: "v"(dst), "v"(pkt) : "memory");
        }
    }
    PROJ(x + DIN);   // proj(1)

    for (int i = 1; i <= T_STEPS; ++i) {
        const int p = (i - 1) & 1;

        // ---- poll own 4 LL units (tag = i): retry-all, start immediately ----
        {
            const u32x2* src = comm + (p * NUNIT) + (tid << 2);
            const u32 tag = (u32)i;
            u32x2 q0, q1, q2, q3;
            for (;;) {
                asm volatile("global_load_dwordx2 %0, %4, off sc0 sc1\n\t"
                             "global_load_dwordx2 %1, %5, off sc0 sc1\n\t"
                             "global_load_dwordx2 %2, %6, off sc0 sc1\n\t"
                             "global_load_dwordx2 %3, %7, off sc0 sc1\n\t"
                             "s_waitcnt vmcnt(0)"
                             : "=&v"(q0), "=&v"(q1), "=&v"(q2), "=&v"(q3)
                             : "v"(src), "v"(src + 1), "v"(src + 2), "v"(src + 3)
                             : "memory");
                u32 ok = (q0.y == tag) & (q1.y == tag) &
                         (q2.y == tag) & (q3.y == tag);
                if (ok) break;
                __builtin_amdgcn_s_sleep(1);
            }
            // unpack 8 bf16 -> f32, stage into s_lds[p][8tid .. 8tid+7]
            f32x4 lo, hi;
            lo[0] = bfLO(q0.x); lo[1] = bfHI(q0.x);
            lo[2] = bfLO(q1.x); lo[3] = bfHI(q1.x);
            hi[0] = bfLO(q2.x); hi[1] = bfHI(q2.x);
            hi[2] = bfLO(q3.x); hi[3] = bfHI(q3.x);
            *(f32x4*)&s_lds[p][tid << 3] = lo;
            *(f32x4*)&s_lds[p][(tid << 3) + 4] = hi;
        }
        __syncthreads();   // the ONLY barrier per step

        if (i < T_STEPS) {
            // ---- matvec: bf16 weights (16 x dwordx4), s from LDS ----
            const f32x4* sbase = (const f32x4*)&s_lds[p][0] + (lane << 1);
            float a0b = 0.f, a1b = 0.f;
#pragma unroll
            for (int c = 0; c < 8; ++c) {
                u32x4 wq0 = *(const u32x4*)(wrow0 + (c << 8));
                u32x4 wq1 = *(const u32x4*)(wrow1 + (c << 8));
                f32x4 sa = sbase[c << 7];
                f32x4 sb = sbase[(c << 7) + 1];
                a0  += bfLO(wq0.x) * sa[0] + bfHI(wq0.x) * sa[1]
                     + bfLO(wq0.y) * sa[2] + bfHI(wq0.y) * sa[3];
                a0b += bfLO(wq0.z) * sb[0] + bfHI(wq0.z) * sb[1]
                     + bfLO(wq0.w) * sb[2] + bfHI(wq0.w) * sb[3];
                a1  += bfLO(wq1.x) * sa[0] + bfHI(wq1.x) * sa[1]
                     + bfLO(wq1.y) * sa[2] + bfHI(wq1.y) * sa[3];
                a1b += bfLO(wq1.z) * sb[0] + bfHI(wq1.z) * sb[1]
                     + bfLO(wq1.w) * sb[2] + bfHI(wq1.w) * sb[3];
            }
            float b = wave_reduce2(a0 + a0b, a1 + a1b, lane);
            float se = __shfl(b, 0) + bias_e;
            float so = __shfl(b, 1) + bias_o;
            float sn_e = (1.f - LEAKF) * s_old_e + LEAKF * fast_tanh(se);
            float sn_o = (1.f - LEAKF) * s_old_o + LEAKF * fast_tanh(so);
            s_old_e = sn_e; s_old_o = sn_o;
            if (lane == 0) {
                u32x2 pkt;
                pkt.x = f2bf(sn_e) | (f2bf(sn_o) << 16);
                pkt.y = (u32)(i + 1);
                u32x2* dst = comm + ((i & 1) * NUNIT) + (bid << 3) + wave;
                asm volatile("global_store_dwordx2 %0, %1, off sc0 sc1"
                             :: "v"(dst), "v"(pkt) : "memory");
            }
        }

        // ---- readout y[i-1]: waves 0,1 each compute one FULL row ----
        // (runs after publish -> overlaps the fabric-latency window)
        if (wave < 2) {
            const float* wrow = wout_lds + wave * NINT;
            float acc = 0.f;
            {   // x part: lane covers 8 of 512
                const float* xr = x + (size_t)(i - 1) * DIN + (lane << 3);
                f32x4 xa = *(const f32x4*)xr;
                f32x4 xb = *(const f32x4*)(xr + 4);
                const f32x4* wr4 = (const f32x4*)wrow + (lane << 1);
                f32x4 wa = wr4[0], wbv = wr4[1];
#pragma unroll
                for (int q = 0; q < 4; ++q)
                    acc += xa[q] * wa[q] + xb[q] * wbv[q];
            }
            {   // s part: 16 x b128 over the 4096 states
                const f32x4* s4 = (const f32x4*)&s_lds[p][0] + lane;
                const f32x4* wr4 = (const f32x4*)(wrow + DIN) + lane;
#pragma unroll
                for (int c = 0; c < 16; ++c) {
                    f32x4 sv = s4[c << 6];
                    f32x4 wv = wr4[c << 6];
#pragma unroll
                    for (int q = 0; q < 4; ++q)
                        acc += sv[q] * wv[q];
                }
            }
            acc += __shfl_xor(acc, 1);
            acc += __shfl_xor(acc, 2);
            acc += __shfl_xor(acc, 4);
            acc += __shfl_xor(acc, 8);
            acc += __shfl_xor(acc, 16);
            acc += __shfl_xor(acc, 32);
            if (lane == 0)
                y[(size_t)(i - 1) * DOUT + (bid << 1) + wave] = acc + wb;
        }

        // ---- proj(i+1) -> fresh a0,a1 for next matvec ----
        if (i + 1 < T_STEPS) PROJ(x + (size_t)(i + 1) * DIN);
    }
#undef PROJ
}

extern "C" void kernel_launch(void* const* d_in, const int* in_sizes, int n_in,
                              void* d_out, int out_size, void* d_ws, size_t ws_size,
                              hipStream_t stream) {
    const float* x      = (const float*)d_in[0];
    const float* Win_w  = (const float*)d_in[1];
    const float* Win_b  = (const float*)d_in[2];
    const float* Wres_w = (const float*)d_in[3];
    const float* Wout_w = (const float*)d_in[4];
    const float* Wout_b = (const float*)d_in[5];
    float* yp = (float*)d_out;

    u32x2* comm   = (u32x2*)d_ws;                        // 32 KB
    u16*   wres_bf = (u16*)((char*)d_ws + 64 * 1024);    // 32 MB bf16 weights

    hipMemsetAsync(d_ws, 0, 2 * NUNIT * sizeof(u32x2), stream);
    conv_bf16<<<2048, 256, 0, stream>>>(Wres_w, (u32*)wres_bf,
                                        R_DIM * R_DIM / 4);

    void* args[] = { (void*)&x, (void*)&Win_w, (void*)&Win_b, (void*)&wres_bf,
                     (void*)&Wout_w, (void*)&Wout_b, (void*)&yp, (void*)&comm };
    hipLaunchCooperativeKernel((void*)esn_fused, dim3(NBLK), dim3(NTHR),
                               args, 0, stream);
}

// Round 15
// 10355.827 us; speedup vs baseline: 2.1589x; 2.1589x over previous
//
#include <hip/hip_runtime.h>

#define T_STEPS 4096
#define DIN     512
#define R_DIM   4096
#define DOUT    512
#define NINT    (R_DIM + DIN)   // 4608
#define NBLK    256
#define NTHR    512
#define NUNIT   2048            // 8B LL units per buffer; unit u = rows {2u,2u+1} bf16
#define LEAKF   0.9f

typedef float f32x4 __attribute__((ext_vector_type(4)));
typedef unsigned int u32;
typedef u32 u32x2 __attribute__((ext_vector_type(2)));

// tanh via hardware exp2: tanh(x) = 1 - 2/(1 + e^{2x})
__device__ __forceinline__ float fast_tanh(float x)
{
    float e = __builtin_amdgcn_exp2f(x * 2.885390081777927f);
    return 1.0f - 2.0f * __builtin_amdgcn_rcpf(1.0f + e);
}

__device__ __forceinline__ u32 f2bf(float f)   // RNE f32 -> bf16 bits
{
    u32 u = __float_as_uint(f);
    return (u + 0x7FFFu + ((u >> 16) & 1u)) >> 16;
}
__device__ __forceinline__ float bfLO(u32 u) { return __uint_as_float(u << 16); }
__device__ __forceinline__ float bfHI(u32 u) { return __uint_as_float(u & 0xFFFF0000u); }

// Butterfly reduce of TWO values across 64 lanes: even lanes end with full
// sum of a0, odd lanes full sum of a1.
__device__ __forceinline__ float wave_reduce2(float a0, float a1, int lane)
{
    a0 += __shfl_xor(a0, 1);
    a1 += __shfl_xor(a1, 1);
    float b = (lane & 1) ? a1 : a0;
    b += __shfl_xor(b, 2);
    b += __shfl_xor(b, 4);
    b += __shfl_xor(b, 8);
    b += __shfl_xor(b, 16);
    b += __shfl_xor(b, 32);
    return b;
}

// ---------------------------------------------------------------------------
// Persistent fused ESN -- EXACT r9 configuration (best measured: 10.34 ms).
// 256 blocks x 512 threads (cooperative, 1 block/CU). Block b owns rows
// [16b,16b+16); wave w owns rows {16b+2w,16b+2w+1} over the FULL K range and
// publishes its own 8B LL unit {bf16 e, bf16 o, u32 tag} autonomously.
// One __syncthreads per step (s_lds parity double-buffered); readout by
// waves 0,1 as complete y-rows after publish (inside the fabric window).
//
// Design ledger (14 rounds of evidence):
//  - poll loop: retry-all, immediate start, s_sleep(1) backoff -- UNTOUCHABLE
//    (r6 early-issue +3.3ms, r10 masked-divergent +2.4ms, r11 delayed +2.2ms)
//  - weights: stream from d_in (compiler remats; AGPR pinning neutral (r7);
//    d_ws-served weights bypass LLC and thrash HBM, r13 +12ms)
//  - producer path: wave-autonomous publish straight after in-wave reduce
//    (cross-wave finalize variants r5/r8 +5ms)
//  - payload: bf16 LL units (r9, -1.9ms vs f32)
//  - compute micro-opts: neutral (r12) -- VALU is not the binding resource
//  - XCD-hierarchical relay: deadlock risk, abandoned (r14)
// Residual floor ~2.5us/step = publish->LLC visibility->catch->barrier chain
// of a chip-wide 16KB broadcast x 4096 sequential steps.
// ---------------------------------------------------------------------------
__global__ __launch_bounds__(NTHR, 2) void esn_fused(
    const float* __restrict__ x,       // (T, DIN)
    const float* __restrict__ Win_w,   // (R, DIN)
    const float* __restrict__ Win_b,   // (R)
    const float* __restrict__ Wres,    // (R, R)
    const float* __restrict__ Wout_w,  // (DOUT, NINT)
    const float* __restrict__ Wout_b,  // (DOUT)
    float* __restrict__ y,             // (T, DOUT)
    u32x2* __restrict__ comm)          // 2 * NUNIT units (d_ws)
{
    const int tid  = threadIdx.x;
    const int wave = tid >> 6;
    const int lane = tid & 63;
    const int bid  = blockIdx.x;
    const int row_e = (bid << 4) + (wave << 1);

    __shared__ float s_lds[2][R_DIM];       // 32 KB, parity double-buffer
    __shared__ float wout_lds[2 * NINT];    // 36.9 KB

    // ---- one-time staging ----
    {
        const float* wsrc = Wout_w + (size_t)(bid << 1) * NINT;
        for (int idx = tid; idx < 2 * NINT; idx += NTHR)
            wout_lds[idx] = wsrc[idx];
    }
    float wb = 0.f;
    if (wave < 2 && lane == 0) wb = Wout_b[(bid << 1) + wave];

    // Wres rows: w[r][c] = Wres[row_e+r][lane*4 + c*256 .. +3]
    f32x4 w[2][16];
    {
        const float* wp = Wres + (size_t)row_e * R_DIM + (lane << 2);
#pragma unroll
        for (int r = 0; r < 2; ++r)
#pragma unroll
            for (int c = 0; c < 16; ++c)
                w[r][c] = *(const f32x4*)(wp + (size_t)r * R_DIM + (c << 8));
    }
    f32x4 win[2][2];
    {
        const float* ip = Win_w + (size_t)row_e * DIN + (lane << 2);
#pragma unroll
        for (int r = 0; r < 2; ++r)
#pragma unroll
            for (int c = 0; c < 2; ++c)
                win[r][c] = *(const f32x4*)(ip + (size_t)r * DIN + (c << 8));
    }
    const float bias_e = Win_b[row_e];
    const float bias_o = Win_b[row_e + 1];
    float s_old_e = 0.f, s_old_o = 0.f;   // lane 0's copy is authoritative

    float a0, a1;

#define PROJ(xrow)                                                        \
    {                                                                     \
        f32x4 xv0 = *(const f32x4*)((xrow) + (lane << 2));                \
        f32x4 xv1 = *(const f32x4*)((xrow) + 256 + (lane << 2));          \
        a0 = 0.f; a1 = 0.f;                                               \
        _Pragma("unroll")                                                 \
        for (int q = 0; q < 4; ++q) {                                     \
            a0 += win[0][0][q] * xv0[q] + win[0][1][q] * xv1[q];          \
            a1 += win[1][0][q] * xv0[q] + win[1][1][q] * xv1[q];          \
        }                                                                 \
    }

    // ---- step 0: s0 = tanh(Win x0 + b); publish tag 1, buffer 0 ----
    {
        PROJ(x);
        float b = wave_reduce2(a0, a1, lane);
        float se = __shfl(b, 0) + bias_e;
        float so = __shfl(b, 1) + bias_o;
        float sn_e = fast_tanh(se);
        float sn_o = fast_tanh(so);
        s_old_e = sn_e; s_old_o = sn_o;
        if (lane == 0) {
            u32x2 pkt;
            pkt.x = f2bf(sn_e) | (f2bf(sn_o) << 16);
            pkt.y = 1u;
            u32x2* dst = comm + (bid << 3) + wave;
            asm volatile("global_store_dwordx2 %0, %1, off sc0 sc1"
                         :: "v"(dst), "v"(pkt) : "memory");
        }
    }
    PROJ(x + DIN);   // proj(1)

    for (int i = 1; i <= T_STEPS; ++i) {
        const int p = (i - 1) & 1;

        // ---- poll own 4 LL units (tag = i), retry-all, single round trip ----
        {
            const u32x2* src = comm + (p * NUNIT) + (tid << 2);
            const u32 tag = (u32)i;
            u32x2 q0, q1, q2, q3;
            for (;;) {
                asm volatile("global_load_dwordx2 %0, %4, off sc0 sc1\n\t"
                             "global_load_dwordx2 %1, %5, off sc0 sc1\n\t"
                             "global_load_dwordx2 %2, %6, off sc0 sc1\n\t"
                             "global_load_dwordx2 %3, %7, off sc0 sc1\n\t"
                             "s_waitcnt vmcnt(0)"
                             : "=&v"(q0), "=&v"(q1), "=&v"(q2), "=&v"(q3)
                             : "v"(src), "v"(src + 1), "v"(src + 2), "v"(src + 3)
                             : "memory");
                u32 ok = (q0.y == tag) & (q1.y == tag) &
                         (q2.y == tag) & (q3.y == tag);
                if (ok) break;
                __builtin_amdgcn_s_sleep(1);
            }
            // unpack 8 bf16 -> f32, stage into s_lds[p][8tid .. 8tid+7]
            f32x4 lo, hi;
            lo[0] = bfLO(q0.x); lo[1] = bfHI(q0.x);
            lo[2] = bfLO(q1.x); lo[3] = bfHI(q1.x);
            hi[0] = bfLO(q2.x); hi[1] = bfHI(q2.x);
            hi[2] = bfLO(q3.x); hi[3] = bfHI(q3.x);
            *(f32x4*)&s_lds[p][tid << 3] = lo;
            *(f32x4*)&s_lds[p][(tid << 3) + 4] = hi;
        }
        __syncthreads();   // the ONLY barrier per step

        if (i < T_STEPS) {
            // ---- matvec: s from LDS (16 x b128) ----
            const f32x4* s4 = (const f32x4*)&s_lds[p][0] + lane;
#pragma unroll
            for (int c = 0; c < 16; ++c) {
                f32x4 sv = s4[c << 6];
#pragma unroll
                for (int q = 0; q < 4; ++q) {
                    a0 += w[0][c][q] * sv[q];
                    a1 += w[1][c][q] * sv[q];
                }
            }
            float b = wave_reduce2(a0, a1, lane);
            float se = __shfl(b, 0) + bias_e;
            float so = __shfl(b, 1) + bias_o;
            float sn_e = (1.f - LEAKF) * s_old_e + LEAKF * fast_tanh(se);
            float sn_o = (1.f - LEAKF) * s_old_o + LEAKF * fast_tanh(so);
            s_old_e = sn_e; s_old_o = sn_o;
            if (lane == 0) {
                u32x2 pkt;
                pkt.x = f2bf(sn_e) | (f2bf(sn_o) << 16);
                pkt.y = (u32)(i + 1);
                u32x2* dst = comm + ((i & 1) * NUNIT) + (bid << 3) + wave;
                asm volatile("global_store_dwordx2 %0, %1, off sc0 sc1"
                             :: "v"(dst), "v"(pkt) : "memory");
            }
        }

        // ---- readout y[i-1]: waves 0,1 each compute one FULL row ----
        // (runs after publish -> overlaps the fabric-latency window)
        if (wave < 2) {
            const float* wrow = wout_lds + wave * NINT;
            float acc = 0.f;
            {   // x part: lane covers 8 of 512
                const float* xr = x + (size_t)(i - 1) * DIN + (lane << 3);
                f32x4 xa = *(const f32x4*)xr;
                f32x4 xb = *(const f32x4*)(xr + 4);
                const f32x4* wr4 = (const f32x4*)wrow + (lane << 1);
                f32x4 wa = wr4[0], wbv = wr4[1];
#pragma unroll
                for (int q = 0; q < 4; ++q)
                    acc += xa[q] * wa[q] + xb[q] * wbv[q];
            }
            {   // s part: 16 x b128 over the 4096 states
                const f32x4* s4 = (const f32x4*)&s_lds[p][0] + lane;
                const f32x4* wr4 = (const f32x4*)(wrow + DIN) + lane;
#pragma unroll
                for (int c = 0; c < 16; ++c) {
                    f32x4 sv = s4[c << 6];
                    f32x4 wv = wr4[c << 6];
#pragma unroll
                    for (int q = 0; q < 4; ++q)
                        acc += sv[q] * wv[q];
                }
            }
            acc += __shfl_xor(acc, 1);
            acc += __shfl_xor(acc, 2);
            acc += __shfl_xor(acc, 4);
            acc += __shfl_xor(acc, 8);
            acc += __shfl_xor(acc, 16);
            acc += __shfl_xor(acc, 32);
            if (lane == 0)
                y[(size_t)(i - 1) * DOUT + (bid << 1) + wave] = acc + wb;
        }

        // ---- proj(i+1) -> fresh a0,a1 for next matvec ----
        if (i + 1 < T_STEPS) PROJ(x + (size_t)(i + 1) * DIN);
    }
#undef PROJ
}

extern "C" void kernel_launch(void* const* d_in, const int* in_sizes, int n_in,
                              void* d_out, int out_size, void* d_ws, size_t ws_size,
                              hipStream_t stream) {
    const float* x      = (const float*)d_in[0];
    const float* Win_w  = (const float*)d_in[1];
    const float* Win_b  = (const float*)d_in[2];
    const float* Wres_w = (const float*)d_in[3];
    const float* Wout_w = (const float*)d_in[4];
    const float* Wout_b = (const float*)d_in[5];
    float* yp = (float*)d_out;

    u32x2* comm = (u32x2*)d_ws;   // 2 * 2048 units * 8 B = 32 KB

    hipMemsetAsync(d_ws, 0, 2 * NUNIT * sizeof(u32x2), stream);

    void* args[] = { (void*)&x, (void*)&Win_w, (void*)&Win_b, (void*)&Wres_w,
                     (void*)&Wout_w, (void*)&Wout_b, (void*)&yp, (void*)&comm };
    hipLaunchCooperativeKernel((void*)esn_fused, dim3(NBLK), dim3(NTHR),
                               args, 0, stream);
}